// Round 5
// baseline (835.364 us; speedup 1.0000x reference)
//
#include <hip/hip_runtime.h>

// ---------------------------------------------------------------------------
// GCN 4-layer inference.
//  - GEMMs: split-bf16 MFMA (hi/lo, 3x mfma_16x16x32_bf16 = ~fp32 accuracy).
//    K-loop: double-buffered LDS, 1 barrier/step, reg-staged prefetch of
//    W(t+1)+A(t+1) issued before compute(t), ds_write after (T14 pattern).
//    Epilogue folds dinv[row], stores aggregation table fp16.
//  - Activations between layers fp16 (exact under split-bf16 re-read).
//  - Aggregation: CSR gather of fp16 rows, 4-deep software-pipelined.
// ---------------------------------------------------------------------------

#define DEV __device__ __forceinline__

typedef __attribute__((ext_vector_type(8))) short short8;
typedef __attribute__((ext_vector_type(4))) float f32x4;
typedef __attribute__((ext_vector_type(4))) _Float16 f16x4;

DEV unsigned short f2bf(float x) {                 // fp32 -> bf16 RNE
    unsigned u = __builtin_bit_cast(unsigned, x);
    u += 0x7FFFu + ((u >> 16) & 1u);
    return (unsigned short)(u >> 16);
}
DEV float bf2f(unsigned short b) {
    return __builtin_bit_cast(float, (unsigned)b << 16);
}

// ---------------- CSR build ----------------

__global__ void k_init(int* __restrict__ cnt, int* __restrict__ fill, int n) {
    int i = blockIdx.x * 256 + threadIdx.x;
    if (i < n) { cnt[i] = 1; fill[i] = 0; }   // 1 = self-loop
}

__global__ void k_count(const int* __restrict__ dst, int* __restrict__ cnt, int E) {
    int e = blockIdx.x * 256 + threadIdx.x;
    if (e < E) atomicAdd(&cnt[dst[e]], 1);
}

__global__ void k_scan1(const int* __restrict__ cnt, int* __restrict__ row_start,
                        int* __restrict__ partial, float* __restrict__ dinv, int n) {
    __shared__ int sdata[256];
    int base = blockIdx.x * 1024;
    int t = threadIdx.x;
    int v[4]; int sum = 0;
#pragma unroll
    for (int j = 0; j < 4; ++j) {
        int idx = base + t * 4 + j;
        v[j] = (idx < n) ? cnt[idx] : 0;
        if (idx < n) dinv[idx] = rsqrtf((float)v[j]);
        sum += v[j];
    }
    sdata[t] = sum;
    __syncthreads();
    for (int off = 1; off < 256; off <<= 1) {
        int x = (t >= off) ? sdata[t - off] : 0;
        __syncthreads();
        sdata[t] += x;
        __syncthreads();
    }
    int excl = sdata[t] - sum;
#pragma unroll
    for (int j = 0; j < 4; ++j) {
        int idx = base + t * 4 + j;
        if (idx < n) row_start[idx] = excl;
        excl += v[j];
    }
    if (t == 255) partial[blockIdx.x] = sdata[255];
}

__global__ void k_scan2(int* __restrict__ partial, int nb) {
    __shared__ int s[128];
    int t = threadIdx.x;
    int v = (t < nb) ? partial[t] : 0;
    s[t] = v;
    __syncthreads();
    for (int off = 1; off < 128; off <<= 1) {
        int x = (t >= off) ? s[t - off] : 0;
        __syncthreads();
        s[t] += x;
        __syncthreads();
    }
    if (t < nb) partial[t] = s[t] - v;
}

__global__ void k_scan3(int* __restrict__ row_start, const int* __restrict__ partial,
                        int n, int total) {
    int i = blockIdx.x * 256 + threadIdx.x;
    if (i < n) row_start[i] += partial[i >> 10];
    if (i == 0) row_start[n] = total;
}

__global__ void k_fill(const int* __restrict__ src, const int* __restrict__ dst,
                       const int* __restrict__ row_start, int* __restrict__ fill,
                       int* __restrict__ csr_src, int E, int n) {
    int i = blockIdx.x * 256 + threadIdx.x;
    int total = E + n;
    if (i >= total) return;
    int s, d;
    if (i < E) { s = src[i]; d = dst[i]; }
    else       { s = d = i - E; }
    int pos = row_start[d] + atomicAdd(&fill[d], 1);
    csr_src[pos] = s;
}

// ---------------- weight decompose: W[N][K] fp32 -> padded bf16 hi/lo ----------------

__global__ void k_wdec(const float* __restrict__ W, int N, int K,
                       unsigned short* __restrict__ Wh, unsigned short* __restrict__ Wl,
                       int NPAD, int KPAD) {
    int i = blockIdx.x * 256 + threadIdx.x;
    if (i >= NPAD * KPAD) return;
    int r = i / KPAD, k = i - r * KPAD;
    float x = (r < N && k < K) ? W[r * K + k] : 0.f;
    unsigned short h = f2bf(x);
    unsigned short l = f2bf(x - bf2f(h));
    Wh[i] = h; Wl[i] = l;
}

// ---------------- MFMA GEMM: H16[m][c] = (A[m][:] . W[c][:]) * dinv[m], fp16 ----------
// 512 thr = 8 waves; BM = 128 rows; wave = 16 rows x NPAD cols.
// Double-buffered LDS (one barrier/step); W(t+1) and A(t+1) prefetched into
// registers before compute(t); W regs written to LDS after the MFMAs.

template <int NF, typename AT>   // NPAD = NF*16
__global__ __launch_bounds__(512, 4)
void gemm_mfma(const AT* __restrict__ A, int lda, int M, int K,
               const unsigned short* __restrict__ Wh,
               const unsigned short* __restrict__ Wl, int ldw,
               const float* __restrict__ dinv,
               _Float16* __restrict__ H16, int ldh, int Nout) {
    constexpr int NPAD = NF * 16;
    constexpr int RB   = 80;               // LDS bytes per 32-elem bf16 row
    constexpr int BUF  = NPAD * RB;        // one half (hi or lo)
    constexpr int CH   = NPAD * 4;         // 16-B chunks per half per K-step
    constexpr int CH2  = 2 * CH;           // hi+lo
    constexpr int NW   = (CH2 + 511) / 512;
    __shared__ char lds[4 * BUF];          // [buf0 hi][buf0 lo][buf1 hi][buf1 lo]

    const int tid  = threadIdx.x;
    const int wv   = tid >> 6;
    const int lane = tid & 63;
    const int lr   = lane & 15;
    const int kq   = lane >> 4;
    const int m0   = blockIdx.x * 128;

    int arow = m0 + wv * 16 + lr;
    if (arow >= M) arow = M - 1;           // clamp; stores are masked
    const AT* Arow = A + (size_t)arow * lda;

    f32x4 acc[NF];
#pragma unroll
    for (int f = 0; f < NF; ++f) acc[f] = (f32x4){0.f, 0.f, 0.f, 0.f};

    const int nsteps = (K + 31) / 32;

    auto loadW = [&](int s, uint4* w) {
        const int kb = s * 32;
#pragma unroll
        for (int j = 0; j < NW; ++j) {
            int c = tid + j * 512;
            if (c < CH2) {
                int b    = (c >= CH);
                int cc   = c - b * CH;
                int r    = cc >> 2;
                int slot = cc & 3;
                w[j] = *(const uint4*)((b ? Wl : Wh) + (size_t)r * ldw + kb + slot * 8);
            }
        }
    };
    auto writeW = [&](char* base, const uint4* w) {
#pragma unroll
        for (int j = 0; j < NW; ++j) {
            int c = tid + j * 512;
            if (c < CH2) {
                int b    = (c >= CH);
                int cc   = c - b * CH;
                int r    = cc >> 2;
                int slot = cc & 3;
                *(uint4*)(base + b * BUF + r * RB + slot * 16) = w[j];
            }
        }
    };
    auto loadA = [&](int s, short8& ahi, short8& alo) {
        const int kb = s * 32 + kq * 8;
        float av[8];
        if (kb + 8 <= K) {
            if constexpr (sizeof(AT) == 4) {
                const float* ap = (const float*)Arow + kb;
                f32x4 v0 = *(const f32x4*)ap;
                f32x4 v1 = *(const f32x4*)(ap + 4);
#pragma unroll
                for (int i = 0; i < 4; ++i) { av[i] = v0[i]; av[4 + i] = v1[i]; }
            } else {
                const _Float16* ap = (const _Float16*)Arow + kb;
                f16x4 v0 = *(const f16x4*)ap;
                f16x4 v1 = *(const f16x4*)(ap + 4);
#pragma unroll
                for (int i = 0; i < 4; ++i) { av[i] = (float)v0[i]; av[4 + i] = (float)v1[i]; }
            }
        } else {
#pragma unroll
            for (int i = 0; i < 8; ++i) {
                int k = kb + i;
                av[i] = (k < K) ? (float)Arow[k] : 0.f;
            }
        }
#pragma unroll
        for (int i = 0; i < 8; ++i) {
            unsigned short h = f2bf(av[i]);
            ahi[i] = (short)h;
            alo[i] = (short)f2bf(av[i] - bf2f(h));
        }
    };
    auto compute = [&](const char* base, const short8& ahi, const short8& alo) {
        const int ro = lr * RB + kq * 16;
#pragma unroll
        for (int f = 0; f < NF; ++f) {
            short8 bh = *(const short8*)(base + f * 16 * RB + ro);
            short8 bl = *(const short8*)(base + BUF + f * 16 * RB + ro);
            acc[f] = __builtin_amdgcn_mfma_f32_16x16x32_bf16(ahi, bh, acc[f], 0, 0, 0);
            acc[f] = __builtin_amdgcn_mfma_f32_16x16x32_bf16(ahi, bl, acc[f], 0, 0, 0);
            acc[f] = __builtin_amdgcn_mfma_f32_16x16x32_bf16(alo, bh, acc[f], 0, 0, 0);
        }
    };

    uint4 wA[NW], wB[NW];
    short8 aAh, aAl, aBh, aBl;

    // prologue: stage step 0 into buf0, load A(0)
    loadW(0, wA);
    loadA(0, aAh, aAl);
    writeW(lds, wA);
    __syncthreads();

    for (int s = 0; s < nsteps; s += 2) {
        const bool p1 = (s + 1 < nsteps);
        if (p1) { loadW(s + 1, wB); loadA(s + 1, aBh, aBl); }
        compute(lds, aAh, aAl);                     // buf0
        if (p1) writeW(lds + 2 * BUF, wB);          // -> buf1
        __syncthreads();
        if (!p1) break;

        const bool p2 = (s + 2 < nsteps);
        if (p2) { loadW(s + 2, wA); loadA(s + 2, aAh, aAl); }
        compute(lds + 2 * BUF, aBh, aBl);           // buf1
        if (p2) writeW(lds, wA);                    // -> buf0
        __syncthreads();
    }

    // store: D row=(lane>>4)*4+j, col=lane&15; scale by dinv[row], cast fp16
    const int rbase = m0 + wv * 16 + kq * 4;
    float dv[4];
#pragma unroll
    for (int j = 0; j < 4; ++j) {
        int row = rbase + j;
        dv[j] = (row < M) ? dinv[row] : 0.f;
    }
#pragma unroll
    for (int f = 0; f < NF; ++f) {
        int col = f * 16 + lr;
        if (col >= Nout) continue;
#pragma unroll
        for (int j = 0; j < 4; ++j) {
            int row = rbase + j;
            if (row < M) H16[(size_t)row * ldh + col] = (_Float16)(acc[f][j] * dv[j]);
        }
    }
}

// ---------------- aggregation: out = dinv[d] * sum_e h16[src_e] + b -----------------
// fp16 gather, 4 features (8 B) per lane; edge loop 4-deep software-pipelined.

template <int F, bool RELU>
__global__ __launch_bounds__(256)
void agg_f16(const _Float16* __restrict__ h, const int* __restrict__ row_start,
             const int* __restrict__ csr_src, const float* __restrict__ dinv,
             const float* __restrict__ bias, _Float16* __restrict__ out, int n) {
    constexpr int LPN = F / 4;
    constexpr int NPW = 64 / LPN;
    int wave = blockIdx.x * 4 + (threadIdx.x >> 6);
    int lane = threadIdx.x & 63;
    int sub  = lane / LPN;
    int fi   = lane - sub * LPN;
    int node = wave * NPW + sub;
    if (sub >= NPW || node >= n) return;
    int f = fi * 4;
    const _Float16* hf = h + f;

    f32x4 acc = {0.f, 0.f, 0.f, 0.f};
    int e0 = row_start[node], e1 = row_start[node + 1];
    int e = e0;
    for (; e + 4 <= e1; e += 4) {
        int s0 = csr_src[e + 0];
        int s1 = csr_src[e + 1];
        int s2 = csr_src[e + 2];
        int s3 = csr_src[e + 3];
        f16x4 v0 = *(const f16x4*)&hf[(size_t)s0 * F];
        f16x4 v1 = *(const f16x4*)&hf[(size_t)s1 * F];
        f16x4 v2 = *(const f16x4*)&hf[(size_t)s2 * F];
        f16x4 v3 = *(const f16x4*)&hf[(size_t)s3 * F];
        acc += __builtin_convertvector(v0, f32x4);
        acc += __builtin_convertvector(v1, f32x4);
        acc += __builtin_convertvector(v2, f32x4);
        acc += __builtin_convertvector(v3, f32x4);
    }
    for (; e < e1; ++e) {
        int s = csr_src[e];
        f16x4 v = *(const f16x4*)&hf[(size_t)s * F];
        acc += __builtin_convertvector(v, f32x4);
    }
    float dn = dinv[node];
    f32x4 b4 = *(const f32x4*)&bias[f];
    acc = acc * dn + b4;
    if (RELU) {
#pragma unroll
        for (int j = 0; j < 4; ++j) acc[j] = fmaxf(acc[j], 0.f);
    }
    f16x4 o;
#pragma unroll
    for (int j = 0; j < 4; ++j) o[j] = (_Float16)acc[j];
    *(f16x4*)&out[(size_t)node * F + f] = o;
}

// ---------------- tiny layer-4 helpers ----------------

__global__ void gemm_small(const _Float16* __restrict__ A, const float* __restrict__ B,
                           const float* __restrict__ dinv, float* __restrict__ C,
                           int M, int K) {
    int m = blockIdx.x * 256 + threadIdx.x;
    if (m >= M) return;
    float a0 = 0.f, a1 = 0.f, a2 = 0.f;
    for (int k = 0; k < K; ++k) {
        float a = (float)A[(size_t)m * K + k];
        a0 += a * B[0 * K + k];
        a1 += a * B[1 * K + k];
        a2 += a * B[2 * K + k];
    }
    float dv = dinv[m];
    C[(size_t)m * 3 + 0] = a0 * dv;
    C[(size_t)m * 3 + 1] = a1 * dv;
    C[(size_t)m * 3 + 2] = a2 * dv;
}

__global__ void agg_f3(const float* __restrict__ h, const int* __restrict__ row_start,
                       const int* __restrict__ csr_src, const float* __restrict__ dinv,
                       const float* __restrict__ bias, float* __restrict__ out, int n) {
    int i = blockIdx.x * 256 + threadIdx.x;
    if (i >= n * 3) return;
    int node = i / 3;
    int f = i - node * 3;
    float acc = 0.f;
    int e1 = row_start[node + 1];
    for (int e = row_start[node]; e < e1; ++e) {
        int s = csr_src[e];
        acc += h[(size_t)s * 3 + f];
    }
    out[i] = acc * dinv[node] + bias[f];
}

// ---------------------------------------------------------------------------

extern "C" void kernel_launch(void* const* d_in, const int* in_sizes, int n_in,
                              void* d_out, int out_size, void* d_ws, size_t ws_size,
                              hipStream_t stream) {
    const float* x   = (const float*)d_in[0];
    const int*   ei  = (const int*)d_in[1];
    const float* W1  = (const float*)d_in[2];
    const float* b1  = (const float*)d_in[3];
    const float* W1b = (const float*)d_in[4];
    const float* b1b = (const float*)d_in[5];
    const float* W2b = (const float*)d_in[6];
    const float* b2b = (const float*)d_in[7];
    const float* W2  = (const float*)d_in[8];
    const float* b2  = (const float*)d_in[9];
    float* out = (float*)d_out;

    const int F_IN = 500, H1 = 200, H2 = 100, H3 = 40;
    const int N = in_sizes[0] / F_IN;
    const int E = in_sizes[1] / 2;
    const int* src = ei;
    const int* dst = ei + E;

    size_t off = 0;
    auto alloc = [&](size_t bytes) -> void* {
        void* p = (char*)d_ws + off;
        off += (bytes + 255) & ~(size_t)255;
        return p;
    };
    int*   cnt       = (int*)  alloc((size_t)N * 4);
    int*   row_start = (int*)  alloc((size_t)(N + 1) * 4);
    int*   fill      = (int*)  alloc((size_t)N * 4);
    int*   partial   = (int*)  alloc(128 * 4);
    float* dinv      = (float*)alloc((size_t)N * 4);
    int*   csr_src   = (int*)  alloc((size_t)(E + N) * 4);
    unsigned short* wh1 = (unsigned short*)alloc(208 * 512 * 2);
    unsigned short* wl1 = (unsigned short*)alloc(208 * 512 * 2);
    unsigned short* wh2 = (unsigned short*)alloc(112 * 224 * 2);
    unsigned short* wl2 = (unsigned short*)alloc(112 * 224 * 2);
    unsigned short* wh3 = (unsigned short*)alloc(48 * 128 * 2);
    unsigned short* wl3 = (unsigned short*)alloc(48 * 128 * 2);
    _Float16* h16   = (_Float16*)alloc((size_t)N * H1 * 2);  // gemm outputs (scaled fp16)
    _Float16* act16 = (_Float16*)alloc((size_t)N * H1 * 2);  // agg outputs (fp16)
    float*    bufC  = (float*)   alloc((size_t)N * 3 * 4);   // layer-4 gemm out

    int gN  = (N + 255) / 256;
    int gE  = (E + 255) / 256;
    int gEN = (E + N + 255) / 256;
    int nb  = (N + 1023) / 1024;

    // --- CSR build ---
    k_init <<<gN, 256, 0, stream>>>(cnt, fill, N);
    k_count<<<gE, 256, 0, stream>>>(dst, cnt, E);
    k_scan1<<<nb, 256, 0, stream>>>(cnt, row_start, partial, dinv, N);
    k_scan2<<<1, 128, 0, stream>>>(partial, nb);
    k_scan3<<<gN, 256, 0, stream>>>(row_start, partial, N, E + N);
    k_fill <<<gEN, 256, 0, stream>>>(src, dst, row_start, fill, csr_src, E, N);

    // --- weight decomposition ---
    k_wdec<<<(208 * 512 + 255) / 256, 256, 0, stream>>>(W1,  H1, F_IN, wh1, wl1, 208, 512);
    k_wdec<<<(112 * 224 + 255) / 256, 256, 0, stream>>>(W1b, H2, H1,   wh2, wl2, 112, 224);
    k_wdec<<<( 48 * 128 + 255) / 256, 256, 0, stream>>>(W2b, H3, H2,   wh3, wl3,  48, 128);

    const int gG = (N + 127) / 128;

    // --- layer 1 ---
    gemm_mfma<13, float><<<gG, 512, 0, stream>>>(x, F_IN, N, F_IN, wh1, wl1, 512,
                                                 dinv, h16, H1, H1);
    agg_f16<200, true><<<(N + 3) / 4, 256, 0, stream>>>(h16, row_start, csr_src, dinv,
                                                        b1, act16, N);
    // --- layer 2 ---
    gemm_mfma<7, _Float16><<<gG, 512, 0, stream>>>(act16, H1, N, H1, wh2, wl2, 224,
                                                   dinv, h16, H2, H2);
    agg_f16<100, true><<<(N / 2 + 3) / 4, 256, 0, stream>>>(h16, row_start, csr_src, dinv,
                                                            b1b, act16, N);
    // --- layer 3 ---
    gemm_mfma<3, _Float16><<<gG, 512, 0, stream>>>(act16, H2, N, H2, wh3, wl3, 128,
                                                   dinv, h16, H3, H3);
    {
        int waves = (N + 5) / 6, blocks = (waves + 3) / 4;
        agg_f16<40, true><<<blocks, 256, 0, stream>>>(h16, row_start, csr_src, dinv,
                                                      b2b, act16, N);
    }
    // --- layer 4 ---
    gemm_small<<<(N + 255) / 256, 256, 0, stream>>>(act16, W2, dinv, bufC, N, H3);
    agg_f3<<<(N * 3 + 255) / 256, 256, 0, stream>>>(bufC, row_start, csr_src, dinv,
                                                    b2, out, N);
}

// Round 6
// 695.510 us; speedup vs baseline: 1.2011x; 1.2011x over previous
//
#include <hip/hip_runtime.h>

// ---------------------------------------------------------------------------
// GCN 4-layer inference.
//  - GEMMs: split-bf16 MFMA (hi/lo, 3x mfma_16x16x32_bf16 = ~fp32 accuracy).
//    K-loop: double-buffered LDS, ONE barrier/step. W(s+1) prefetched into
//    named regs (statically-indexed arrays, no pointer-lambdas -> no scratch),
//    A(s+1) prefetched by-value; ds_write of W(s+1) AFTER the MFMAs.
//    LDS rows 64 B + slot-XOR swizzle (involution on write & read).
//  - Activations between layers fp16 (exact under split-bf16 re-read).
//  - Aggregation: CSR gather of fp16 rows, 4-deep software-pipelined.
// ---------------------------------------------------------------------------

#define DEV __device__ __forceinline__

typedef __attribute__((ext_vector_type(8))) short short8;
typedef __attribute__((ext_vector_type(4))) float f32x4;
typedef __attribute__((ext_vector_type(4))) _Float16 f16x4;

DEV unsigned short f2bf(float x) {                 // fp32 -> bf16 RNE
    unsigned u = __builtin_bit_cast(unsigned, x);
    u += 0x7FFFu + ((u >> 16) & 1u);
    return (unsigned short)(u >> 16);
}
DEV float bf2f(unsigned short b) {
    return __builtin_bit_cast(float, (unsigned)b << 16);
}

// ---------------- CSR build ----------------

__global__ void k_init(int* __restrict__ cnt, int* __restrict__ fill, int n) {
    int i = blockIdx.x * 256 + threadIdx.x;
    if (i < n) { cnt[i] = 1; fill[i] = 0; }   // 1 = self-loop
}

__global__ void k_count(const int* __restrict__ dst, int* __restrict__ cnt, int E) {
    int e = blockIdx.x * 256 + threadIdx.x;
    if (e < E) atomicAdd(&cnt[dst[e]], 1);
}

__global__ void k_scan1(const int* __restrict__ cnt, int* __restrict__ row_start,
                        int* __restrict__ partial, float* __restrict__ dinv, int n) {
    __shared__ int sdata[256];
    int base = blockIdx.x * 1024;
    int t = threadIdx.x;
    int v[4]; int sum = 0;
#pragma unroll
    for (int j = 0; j < 4; ++j) {
        int idx = base + t * 4 + j;
        v[j] = (idx < n) ? cnt[idx] : 0;
        if (idx < n) dinv[idx] = rsqrtf((float)v[j]);
        sum += v[j];
    }
    sdata[t] = sum;
    __syncthreads();
    for (int off = 1; off < 256; off <<= 1) {
        int x = (t >= off) ? sdata[t - off] : 0;
        __syncthreads();
        sdata[t] += x;
        __syncthreads();
    }
    int excl = sdata[t] - sum;
#pragma unroll
    for (int j = 0; j < 4; ++j) {
        int idx = base + t * 4 + j;
        if (idx < n) row_start[idx] = excl;
        excl += v[j];
    }
    if (t == 255) partial[blockIdx.x] = sdata[255];
}

__global__ void k_scan2(int* __restrict__ partial, int nb) {
    __shared__ int s[128];
    int t = threadIdx.x;
    int v = (t < nb) ? partial[t] : 0;
    s[t] = v;
    __syncthreads();
    for (int off = 1; off < 128; off <<= 1) {
        int x = (t >= off) ? s[t - off] : 0;
        __syncthreads();
        s[t] += x;
        __syncthreads();
    }
    if (t < nb) partial[t] = s[t] - v;
}

__global__ void k_scan3(int* __restrict__ row_start, const int* __restrict__ partial,
                        int n, int total) {
    int i = blockIdx.x * 256 + threadIdx.x;
    if (i < n) row_start[i] += partial[i >> 10];
    if (i == 0) row_start[n] = total;
}

__global__ void k_fill(const int* __restrict__ src, const int* __restrict__ dst,
                       const int* __restrict__ row_start, int* __restrict__ fill,
                       int* __restrict__ csr_src, int E, int n) {
    int i = blockIdx.x * 256 + threadIdx.x;
    int total = E + n;
    if (i >= total) return;
    int s, d;
    if (i < E) { s = src[i]; d = dst[i]; }
    else       { s = d = i - E; }
    int pos = row_start[d] + atomicAdd(&fill[d], 1);
    csr_src[pos] = s;
}

// ---------------- weight decompose: W[N][K] fp32 -> padded bf16 hi/lo ----------------

__global__ void k_wdec(const float* __restrict__ W, int N, int K,
                       unsigned short* __restrict__ Wh, unsigned short* __restrict__ Wl,
                       int NPAD, int KPAD) {
    int i = blockIdx.x * 256 + threadIdx.x;
    if (i >= NPAD * KPAD) return;
    int r = i / KPAD, k = i - r * KPAD;
    float x = (r < N && k < K) ? W[r * K + k] : 0.f;
    unsigned short h = f2bf(x);
    unsigned short l = f2bf(x - bf2f(h));
    Wh[i] = h; Wl[i] = l;
}

// ---------------- MFMA GEMM: H16[m][c] = (A[m][:] . W[c][:]) * dinv[m], fp16 ----------
// 512 thr = 8 waves; BM = 128 rows; wave = 16 rows x NPAD cols.
// Double-buffered LDS (64-B rows, slot-XOR swizzled), one barrier per K-step.
// W(s+1)+A(s+1) issued before compute(s); W ds_write after the MFMAs.

struct A8 { f32x4 lo, hi; };

template <int NF, typename AT>   // NPAD = NF*16
__global__ __launch_bounds__(512)
void gemm_mfma(const AT* __restrict__ A, int lda, int M, int K,
               const unsigned short* __restrict__ Wh,
               const unsigned short* __restrict__ Wl, int ldw,
               const float* __restrict__ dinv,
               _Float16* __restrict__ H16, int ldh, int Nout) {
    constexpr int NPAD = NF * 16;
    constexpr int HBUF = NPAD * 64;        // bytes per half (hi or lo)
    constexpr int BUFB = 2 * HBUF;         // one K-step buffer (hi+lo)
    constexpr int CH   = NPAD * 4;         // 16-B chunks per half
    constexpr int CH2  = 2 * CH;
    constexpr int NW   = (CH2 + 511) / 512;
    __shared__ char lds[2 * BUFB];

    const int tid  = threadIdx.x;
    const int wv   = tid >> 6;
    const int lane = tid & 63;
    const int lr   = lane & 15;
    const int kq   = lane >> 4;
    const int m0   = blockIdx.x * 128;

    int arow = m0 + wv * 16 + lr;
    if (arow >= M) arow = M - 1;           // clamp; stores masked
    const AT* Arow = A + (size_t)arow * lda;

    // per-thread W-chunk decode, hoisted out of the K-loop
    const unsigned short* wgp[NW];         // global src (swizzled slot), statically indexed
    int  wlo[NW];                          // lds byte offset within buffer
    bool wok[NW];
#pragma unroll
    for (int j = 0; j < NW; ++j) {
        int c  = tid + j * 512;
        wok[j] = (c < CH2);
        int cw = wok[j] ? c : 0;
        int b  = (cw >= CH) ? 1 : 0;
        int cc = cw - b * CH;
        int r  = cc >> 2;
        int sl = cc & 3;
        int gs = sl ^ (r & 3);             // involutory slot swizzle
        wgp[j] = (b ? Wl : Wh) + (size_t)r * ldw + gs * 8;
        wlo[j] = b * HBUF + r * 64 + sl * 16;
    }

    auto loadA = [&](int s) -> A8 {
        A8 o;
        int kb = s * 32 + kq * 8;
        if (kb + 8 <= K) {
            if constexpr (sizeof(AT) == 4) {
                const float* ap = (const float*)Arow + kb;
                o.lo = *(const f32x4*)ap;
                o.hi = *(const f32x4*)(ap + 4);
            } else {
                const _Float16* ap = (const _Float16*)Arow + kb;
                f16x4 v0 = *(const f16x4*)ap;
                f16x4 v1 = *(const f16x4*)(ap + 4);
                o.lo = __builtin_convertvector(v0, f32x4);
                o.hi = __builtin_convertvector(v1, f32x4);
            }
        } else {
#pragma unroll
            for (int i = 0; i < 4; ++i) {
                int k0 = kb + i, k1 = kb + 4 + i;
                o.lo[i] = (k0 < K) ? (float)Arow[k0] : 0.f;
                o.hi[i] = (k1 < K) ? (float)Arow[k1] : 0.f;
            }
        }
        return o;
    };

    f32x4 acc[NF];
#pragma unroll
    for (int f = 0; f < NF; ++f) acc[f] = (f32x4){0.f, 0.f, 0.f, 0.f};

    const int nsteps = (K + 31) / 32;
    uint4 wreg[NW];

    // ---- prologue: W(0)+A(0) ----
#pragma unroll
    for (int j = 0; j < NW; ++j)
        if (wok[j]) wreg[j] = *(const uint4*)(wgp[j]);
    A8 acur = loadA(0);
#pragma unroll
    for (int j = 0; j < NW; ++j)
        if (wok[j]) *(uint4*)(lds + wlo[j]) = wreg[j];
    __syncthreads();

    const int ro = lr * 64 + ((kq ^ (lr & 3)) << 4);   // swizzled read offset

    for (int s = 0; s < nsteps; ++s) {
        const char* bb = lds + (s & 1) * BUFB;
        char*       bn = lds + ((s + 1) & 1) * BUFB;
        const bool more = (s + 1 < nsteps);

        // issue next-step W + A loads (latency hides under MFMAs below)
        if (more) {
#pragma unroll
            for (int j = 0; j < NW; ++j)
                if (wok[j]) wreg[j] = *(const uint4*)(wgp[j] + (size_t)(s + 1) * 32);
        }
        A8 anxt;
        if (more) anxt = loadA(s + 1);
        else      { anxt.lo = (f32x4){0,0,0,0}; anxt.hi = (f32x4){0,0,0,0}; }

        // convert current A -> bf16 hi/lo
        float av[8];
#pragma unroll
        for (int i = 0; i < 4; ++i) { av[i] = acur.lo[i]; av[4 + i] = acur.hi[i]; }
        short8 ahi, alo;
#pragma unroll
        for (int i = 0; i < 8; ++i) {
            unsigned short h = f2bf(av[i]);
            ahi[i] = (short)h;
            alo[i] = (short)f2bf(av[i] - bf2f(h));
        }

        // MFMAs on current buffer
#pragma unroll
        for (int f = 0; f < NF; ++f) {
            short8 bh = *(const short8*)(bb + f * 1024 + ro);
            short8 bl = *(const short8*)(bb + HBUF + f * 1024 + ro);
            acc[f] = __builtin_amdgcn_mfma_f32_16x16x32_bf16(ahi, bh, acc[f], 0, 0, 0);
            acc[f] = __builtin_amdgcn_mfma_f32_16x16x32_bf16(ahi, bl, acc[f], 0, 0, 0);
            acc[f] = __builtin_amdgcn_mfma_f32_16x16x32_bf16(alo, bh, acc[f], 0, 0, 0);
        }

        // write next-step W into the other buffer, then single barrier
        if (more) {
#pragma unroll
            for (int j = 0; j < NW; ++j)
                if (wok[j]) *(uint4*)(bn + wlo[j]) = wreg[j];
        }
        __syncthreads();
        acur = anxt;
    }

    // store: D row=(lane>>4)*4+j, col=lane&15; scale by dinv[row], cast fp16
    const int rbase = m0 + wv * 16 + kq * 4;
    float dv[4];
#pragma unroll
    for (int j = 0; j < 4; ++j) {
        int row = rbase + j;
        dv[j] = (row < M) ? dinv[row] : 0.f;
    }
#pragma unroll
    for (int f = 0; f < NF; ++f) {
        int col = f * 16 + lr;
        if (col >= Nout) continue;
#pragma unroll
        for (int j = 0; j < 4; ++j) {
            int row = rbase + j;
            if (row < M) H16[(size_t)row * ldh + col] = (_Float16)(acc[f][j] * dv[j]);
        }
    }
}

// ---------------- aggregation: out = dinv[d] * sum_e h16[src_e] + b -----------------
// fp16 gather, 4 features (8 B) per lane; edge loop 4-deep software-pipelined.

template <int F, bool RELU>
__global__ __launch_bounds__(256)
void agg_f16(const _Float16* __restrict__ h, const int* __restrict__ row_start,
             const int* __restrict__ csr_src, const float* __restrict__ dinv,
             const float* __restrict__ bias, _Float16* __restrict__ out, int n) {
    constexpr int LPN = F / 4;
    constexpr int NPW = 64 / LPN;
    int wave = blockIdx.x * 4 + (threadIdx.x >> 6);
    int lane = threadIdx.x & 63;
    int sub  = lane / LPN;
    int fi   = lane - sub * LPN;
    int node = wave * NPW + sub;
    if (sub >= NPW || node >= n) return;
    int f = fi * 4;
    const _Float16* hf = h + f;

    f32x4 acc = {0.f, 0.f, 0.f, 0.f};
    int e0 = row_start[node], e1 = row_start[node + 1];
    int e = e0;
    for (; e + 4 <= e1; e += 4) {
        int s0 = csr_src[e + 0];
        int s1 = csr_src[e + 1];
        int s2 = csr_src[e + 2];
        int s3 = csr_src[e + 3];
        f16x4 v0 = *(const f16x4*)&hf[(size_t)s0 * F];
        f16x4 v1 = *(const f16x4*)&hf[(size_t)s1 * F];
        f16x4 v2 = *(const f16x4*)&hf[(size_t)s2 * F];
        f16x4 v3 = *(const f16x4*)&hf[(size_t)s3 * F];
        acc += __builtin_convertvector(v0, f32x4);
        acc += __builtin_convertvector(v1, f32x4);
        acc += __builtin_convertvector(v2, f32x4);
        acc += __builtin_convertvector(v3, f32x4);
    }
    for (; e < e1; ++e) {
        int s = csr_src[e];
        f16x4 v = *(const f16x4*)&hf[(size_t)s * F];
        acc += __builtin_convertvector(v, f32x4);
    }
    float dn = dinv[node];
    f32x4 b4 = *(const f32x4*)&bias[f];
    acc = acc * dn + b4;
    if (RELU) {
#pragma unroll
        for (int j = 0; j < 4; ++j) acc[j] = fmaxf(acc[j], 0.f);
    }
    f16x4 o;
#pragma unroll
    for (int j = 0; j < 4; ++j) o[j] = (_Float16)acc[j];
    *(f16x4*)&out[(size_t)node * F + f] = o;
}

// ---------------- tiny layer-4 helpers ----------------

__global__ void gemm_small(const _Float16* __restrict__ A, const float* __restrict__ B,
                           const float* __restrict__ dinv, float* __restrict__ C,
                           int M, int K) {
    int m = blockIdx.x * 256 + threadIdx.x;
    if (m >= M) return;
    float a0 = 0.f, a1 = 0.f, a2 = 0.f;
    for (int k = 0; k < K; ++k) {
        float a = (float)A[(size_t)m * K + k];
        a0 += a * B[0 * K + k];
        a1 += a * B[1 * K + k];
        a2 += a * B[2 * K + k];
    }
    float dv = dinv[m];
    C[(size_t)m * 3 + 0] = a0 * dv;
    C[(size_t)m * 3 + 1] = a1 * dv;
    C[(size_t)m * 3 + 2] = a2 * dv;
}

__global__ void agg_f3(const float* __restrict__ h, const int* __restrict__ row_start,
                       const int* __restrict__ csr_src, const float* __restrict__ dinv,
                       const float* __restrict__ bias, float* __restrict__ out, int n) {
    int i = blockIdx.x * 256 + threadIdx.x;
    if (i >= n * 3) return;
    int node = i / 3;
    int f = i - node * 3;
    float acc = 0.f;
    int e1 = row_start[node + 1];
    for (int e = row_start[node]; e < e1; ++e) {
        int s = csr_src[e];
        acc += h[(size_t)s * 3 + f];
    }
    out[i] = acc * dinv[node] + bias[f];
}

// ---------------------------------------------------------------------------

extern "C" void kernel_launch(void* const* d_in, const int* in_sizes, int n_in,
                              void* d_out, int out_size, void* d_ws, size_t ws_size,
                              hipStream_t stream) {
    const float* x   = (const float*)d_in[0];
    const int*   ei  = (const int*)d_in[1];
    const float* W1  = (const float*)d_in[2];
    const float* b1  = (const float*)d_in[3];
    const float* W1b = (const float*)d_in[4];
    const float* b1b = (const float*)d_in[5];
    const float* W2b = (const float*)d_in[6];
    const float* b2b = (const float*)d_in[7];
    const float* W2  = (const float*)d_in[8];
    const float* b2  = (const float*)d_in[9];
    float* out = (float*)d_out;

    const int F_IN = 500, H1 = 200, H2 = 100, H3 = 40;
    const int N = in_sizes[0] / F_IN;
    const int E = in_sizes[1] / 2;
    const int* src = ei;
    const int* dst = ei + E;

    size_t off = 0;
    auto alloc = [&](size_t bytes) -> void* {
        void* p = (char*)d_ws + off;
        off += (bytes + 255) & ~(size_t)255;
        return p;
    };
    int*   cnt       = (int*)  alloc((size_t)N * 4);
    int*   row_start = (int*)  alloc((size_t)(N + 1) * 4);
    int*   fill      = (int*)  alloc((size_t)N * 4);
    int*   partial   = (int*)  alloc(128 * 4);
    float* dinv      = (float*)alloc((size_t)N * 4);
    int*   csr_src   = (int*)  alloc((size_t)(E + N) * 4);
    unsigned short* wh1 = (unsigned short*)alloc(208 * 512 * 2);
    unsigned short* wl1 = (unsigned short*)alloc(208 * 512 * 2);
    unsigned short* wh2 = (unsigned short*)alloc(112 * 224 * 2);
    unsigned short* wl2 = (unsigned short*)alloc(112 * 224 * 2);
    unsigned short* wh3 = (unsigned short*)alloc(48 * 128 * 2);
    unsigned short* wl3 = (unsigned short*)alloc(48 * 128 * 2);
    _Float16* h16   = (_Float16*)alloc((size_t)N * H1 * 2);  // gemm outputs (scaled fp16)
    _Float16* act16 = (_Float16*)alloc((size_t)N * H1 * 2);  // agg outputs (fp16)
    float*    bufC  = (float*)   alloc((size_t)N * 3 * 4);   // layer-4 gemm out

    int gN  = (N + 255) / 256;
    int gE  = (E + 255) / 256;
    int gEN = (E + N + 255) / 256;
    int nb  = (N + 1023) / 1024;

    // --- CSR build ---
    k_init <<<gN, 256, 0, stream>>>(cnt, fill, N);
    k_count<<<gE, 256, 0, stream>>>(dst, cnt, E);
    k_scan1<<<nb, 256, 0, stream>>>(cnt, row_start, partial, dinv, N);
    k_scan2<<<1, 128, 0, stream>>>(partial, nb);
    k_scan3<<<gN, 256, 0, stream>>>(row_start, partial, N, E + N);
    k_fill <<<gEN, 256, 0, stream>>>(src, dst, row_start, fill, csr_src, E, N);

    // --- weight decomposition ---
    k_wdec<<<(208 * 512 + 255) / 256, 256, 0, stream>>>(W1,  H1, F_IN, wh1, wl1, 208, 512);
    k_wdec<<<(112 * 224 + 255) / 256, 256, 0, stream>>>(W1b, H2, H1,   wh2, wl2, 112, 224);
    k_wdec<<<( 48 * 128 + 255) / 256, 256, 0, stream>>>(W2b, H3, H2,   wh3, wl3,  48, 128);

    const int gG = (N + 127) / 128;

    // --- layer 1 ---
    gemm_mfma<13, float><<<gG, 512, 0, stream>>>(x, F_IN, N, F_IN, wh1, wl1, 512,
                                                 dinv, h16, H1, H1);
    agg_f16<200, true><<<(N + 3) / 4, 256, 0, stream>>>(h16, row_start, csr_src, dinv,
                                                        b1, act16, N);
    // --- layer 2 ---
    gemm_mfma<7, _Float16><<<gG, 512, 0, stream>>>(act16, H1, N, H1, wh2, wl2, 224,
                                                   dinv, h16, H2, H2);
    agg_f16<100, true><<<(N / 2 + 3) / 4, 256, 0, stream>>>(h16, row_start, csr_src, dinv,
                                                            b1b, act16, N);
    // --- layer 3 ---
    gemm_mfma<3, _Float16><<<gG, 512, 0, stream>>>(act16, H2, N, H2, wh3, wl3, 128,
                                                   dinv, h16, H3, H3);
    {
        int waves = (N + 5) / 6, blocks = (waves + 3) / 4;
        agg_f16<40, true><<<blocks, 256, 0, stream>>>(h16, row_start, csr_src, dinv,
                                                      b2b, act16, N);
    }
    // --- layer 4 ---
    gemm_small<<<(N + 255) / 256, 256, 0, stream>>>(act16, W2, dinv, bufC, N, H3);
    agg_f3<<<(N * 3 + 255) / 256, 256, 0, stream>>>(bufC, row_start, csr_src, dinv,
                                                    b2, out, N);
}

// Round 7
// 576.829 us; speedup vs baseline: 1.4482x; 1.2057x over previous
//
#include <hip/hip_runtime.h>

// ---------------------------------------------------------------------------
// GCN 4-layer inference.
//  - GEMMs: split-bf16 MFMA (hi/lo, 3x mfma_16x16x32_bf16 = ~fp32 accuracy).
//    K-loop: double-buffered LDS, ONE barrier/step. W(s+1) staged via
//    global_load_lds (DMA, no VGPRs, pre-swizzled global source);
//    A(s+1) prefetched by-value in regs. launch_bounds(512,2) = no spill.
//  - Activations between layers fp16 (exact under split-bf16 re-read).
//  - Aggregation: CSR gather of fp16 rows, 4-deep software-pipelined.
// ---------------------------------------------------------------------------

#define DEV __device__ __forceinline__

typedef __attribute__((ext_vector_type(8))) short short8;
typedef __attribute__((ext_vector_type(4))) float f32x4;
typedef __attribute__((ext_vector_type(4))) _Float16 f16x4;

DEV unsigned short f2bf(float x) {                 // fp32 -> bf16 RNE
    unsigned u = __builtin_bit_cast(unsigned, x);
    u += 0x7FFFu + ((u >> 16) & 1u);
    return (unsigned short)(u >> 16);
}
DEV float bf2f(unsigned short b) {
    return __builtin_bit_cast(float, (unsigned)b << 16);
}

DEV void gload_lds16(const void* g, void* l) {     // 16-B DMA global -> LDS
    __builtin_amdgcn_global_load_lds(
        (const __attribute__((address_space(1))) unsigned int*)g,
        (__attribute__((address_space(3))) unsigned int*)l, 16, 0, 0);
}

// ---------------- CSR build ----------------

__global__ void k_init(int* __restrict__ cnt, int* __restrict__ fill, int n) {
    int i = blockIdx.x * 256 + threadIdx.x;
    if (i < n) { cnt[i] = 1; fill[i] = 0; }   // 1 = self-loop
}

__global__ void k_count(const int* __restrict__ dst, int* __restrict__ cnt, int E) {
    int e = blockIdx.x * 256 + threadIdx.x;
    if (e < E) atomicAdd(&cnt[dst[e]], 1);
}

__global__ void k_scan1(const int* __restrict__ cnt, int* __restrict__ row_start,
                        int* __restrict__ partial, float* __restrict__ dinv, int n) {
    __shared__ int sdata[256];
    int base = blockIdx.x * 1024;
    int t = threadIdx.x;
    int v[4]; int sum = 0;
#pragma unroll
    for (int j = 0; j < 4; ++j) {
        int idx = base + t * 4 + j;
        v[j] = (idx < n) ? cnt[idx] : 0;
        if (idx < n) dinv[idx] = rsqrtf((float)v[j]);
        sum += v[j];
    }
    sdata[t] = sum;
    __syncthreads();
    for (int off = 1; off < 256; off <<= 1) {
        int x = (t >= off) ? sdata[t - off] : 0;
        __syncthreads();
        sdata[t] += x;
        __syncthreads();
    }
    int excl = sdata[t] - sum;
#pragma unroll
    for (int j = 0; j < 4; ++j) {
        int idx = base + t * 4 + j;
        if (idx < n) row_start[idx] = excl;
        excl += v[j];
    }
    if (t == 255) partial[blockIdx.x] = sdata[255];
}

__global__ void k_scan2(int* __restrict__ partial, int nb) {
    __shared__ int s[128];
    int t = threadIdx.x;
    int v = (t < nb) ? partial[t] : 0;
    s[t] = v;
    __syncthreads();
    for (int off = 1; off < 128; off <<= 1) {
        int x = (t >= off) ? s[t - off] : 0;
        __syncthreads();
        s[t] += x;
        __syncthreads();
    }
    if (t < nb) partial[t] = s[t] - v;
}

__global__ void k_scan3(int* __restrict__ row_start, const int* __restrict__ partial,
                        int n, int total) {
    int i = blockIdx.x * 256 + threadIdx.x;
    if (i < n) row_start[i] += partial[i >> 10];
    if (i == 0) row_start[n] = total;
}

__global__ void k_fill(const int* __restrict__ src, const int* __restrict__ dst,
                       const int* __restrict__ row_start, int* __restrict__ fill,
                       int* __restrict__ csr_src, int E, int n) {
    int i = blockIdx.x * 256 + threadIdx.x;
    int total = E + n;
    if (i >= total) return;
    int s, d;
    if (i < E) { s = src[i]; d = dst[i]; }
    else       { s = d = i - E; }
    int pos = row_start[d] + atomicAdd(&fill[d], 1);
    csr_src[pos] = s;
}

// ---------------- weight decompose: W[N][K] fp32 -> padded bf16 hi/lo ----------------

__global__ void k_wdec(const float* __restrict__ W, int N, int K,
                       unsigned short* __restrict__ Wh, unsigned short* __restrict__ Wl,
                       int NPAD, int KPAD) {
    int i = blockIdx.x * 256 + threadIdx.x;
    if (i >= NPAD * KPAD) return;
    int r = i / KPAD, k = i - r * KPAD;
    float x = (r < N && k < K) ? W[r * K + k] : 0.f;
    unsigned short h = f2bf(x);
    unsigned short l = f2bf(x - bf2f(h));
    Wh[i] = h; Wl[i] = l;
}

// ---------------- MFMA GEMM: H16[m][c] = (A[m][:] . W[c][:]) * dinv[m], fp16 ----------
// 512 thr = 8 waves; BM = 128 rows; wave = 16 rows x NPAD cols.
// Double-buffered LDS, one barrier/step. W(s+1) via global_load_lds with
// pre-swizzled global source (linear LDS dest); swizzled ds_read on consume.

struct A8 { f32x4 lo, hi; };

template <int NF, typename AT>   // NPAD = NF*16
__global__ __launch_bounds__(512, 2)
void gemm_mfma(const AT* __restrict__ A, int lda, int M, int K,
               const unsigned short* __restrict__ Wh,
               const unsigned short* __restrict__ Wl, int ldw,
               const float* __restrict__ dinv,
               _Float16* __restrict__ H16, int ldh, int Nout) {
    constexpr int NPAD = NF * 16;
    constexpr int HBUF = NPAD * 64;        // bytes per half (hi or lo)
    constexpr int BUFB = 2 * HBUF;         // one K-step buffer (hi+lo)
    constexpr int CH   = NPAD * 4;         // 16-B chunks per half
    constexpr int CH2  = 2 * CH;           // total chunks per step
    constexpr int NISS = CH2 / 64;         // wave-issues per step (multiple of 2)
    __shared__ char lds[2 * BUFB];

    const int tid  = threadIdx.x;
    const int wv   = tid >> 6;
    const int lane = tid & 63;
    const int lr   = lane & 15;
    const int kq   = lane >> 4;
    const int m0   = blockIdx.x * 128;

    int arow = m0 + wv * 16 + lr;
    if (arow >= M) arow = M - 1;           // clamp; stores masked
    const AT* Arow = A + (size_t)arow * lda;

    // this lane's chunk geometry for each of its staging issues (static arrays)
    // chunk c = i*64 + lane; half = c>=CH; row r = cc>>2; slot sl = cc&3;
    // global slot gs = sl ^ (r&3)  (involutory swizzle, applied source-side)
    auto stageW = [&](int s, int bufsel) {
        const int kb = s * 32;
        char* base = lds + bufsel * BUFB;
        for (int i = wv; i < NISS; i += 8) {
            int c  = i * 64 + lane;
            int h  = (c >= CH) ? 1 : 0;
            int cc = c - h * CH;
            int r  = cc >> 2;
            int sl = cc & 3;
            int gs = sl ^ (r & 3);
            const unsigned short* gp = (h ? Wl : Wh) + (size_t)r * ldw + kb + gs * 8;
            gload_lds16(gp, base + i * 1024);
        }
    };

    auto loadA = [&](int s) -> A8 {
        A8 o;
        int kb = s * 32 + kq * 8;
        if (kb + 8 <= K) {
            if constexpr (sizeof(AT) == 4) {
                const float* ap = (const float*)Arow + kb;
                o.lo = *(const f32x4*)ap;
                o.hi = *(const f32x4*)(ap + 4);
            } else {
                const _Float16* ap = (const _Float16*)Arow + kb;
                f16x4 v0 = *(const f16x4*)ap;
                f16x4 v1 = *(const f16x4*)(ap + 4);
                o.lo = __builtin_convertvector(v0, f32x4);
                o.hi = __builtin_convertvector(v1, f32x4);
            }
        } else {
#pragma unroll
            for (int i = 0; i < 4; ++i) {
                int k0 = kb + i, k1 = kb + 4 + i;
                o.lo[i] = (k0 < K) ? (float)Arow[k0] : 0.f;
                o.hi[i] = (k1 < K) ? (float)Arow[k1] : 0.f;
            }
        }
        return o;
    };

    f32x4 acc[NF];
#pragma unroll
    for (int f = 0; f < NF; ++f) acc[f] = (f32x4){0.f, 0.f, 0.f, 0.f};

    const int nsteps = (K + 31) / 32;

    // ---- prologue: stage W(0), load A(0) ----
    stageW(0, 0);
    A8 acur = loadA(0);
    __syncthreads();                       // drains vmcnt -> W(0) visible

    const int ro = lr * 64 + ((kq ^ (lr & 3)) << 4);   // swizzled read offset

    for (int s = 0; s < nsteps; ++s) {
        const char* bb = lds + (s & 1) * BUFB;
        const bool more = (s + 1 < nsteps);

        // issue next-step staging + A prefetch BEFORE compute (latency hides)
        if (more) stageW(s + 1, (s + 1) & 1);
        A8 anxt;
        if (more) anxt = loadA(s + 1);
        else      { anxt.lo = (f32x4){0,0,0,0}; anxt.hi = (f32x4){0,0,0,0}; }

        // convert current A -> bf16 hi/lo
        float av[8];
#pragma unroll
        for (int i = 0; i < 4; ++i) { av[i] = acur.lo[i]; av[4 + i] = acur.hi[i]; }
        short8 ahi, alo;
#pragma unroll
        for (int i = 0; i < 8; ++i) {
            unsigned short h = f2bf(av[i]);
            ahi[i] = (short)h;
            alo[i] = (short)f2bf(av[i] - bf2f(h));
        }

        // MFMAs on current buffer
#pragma unroll
        for (int f = 0; f < NF; ++f) {
            short8 bh = *(const short8*)(bb + f * 1024 + ro);
            short8 bl = *(const short8*)(bb + HBUF + f * 1024 + ro);
            acc[f] = __builtin_amdgcn_mfma_f32_16x16x32_bf16(ahi, bh, acc[f], 0, 0, 0);
            acc[f] = __builtin_amdgcn_mfma_f32_16x16x32_bf16(ahi, bl, acc[f], 0, 0, 0);
            acc[f] = __builtin_amdgcn_mfma_f32_16x16x32_bf16(alo, bh, acc[f], 0, 0, 0);
        }

        __syncthreads();                   // drains vmcnt -> W(s+1) visible
        acur = anxt;
    }

    // store: D row=(lane>>4)*4+j, col=lane&15; scale by dinv[row], cast fp16
    const int rbase = m0 + wv * 16 + kq * 4;
    float dv[4];
#pragma unroll
    for (int j = 0; j < 4; ++j) {
        int row = rbase + j;
        dv[j] = (row < M) ? dinv[row] : 0.f;
    }
#pragma unroll
    for (int f = 0; f < NF; ++f) {
        int col = f * 16 + lr;
        if (col >= Nout) continue;
#pragma unroll
        for (int j = 0; j < 4; ++j) {
            int row = rbase + j;
            if (row < M) H16[(size_t)row * ldh + col] = (_Float16)(acc[f][j] * dv[j]);
        }
    }
}

// ---------------- aggregation: out = dinv[d] * sum_e h16[src_e] + b -----------------
// fp16 gather, 4 features (8 B) per lane; edge loop 4-deep software-pipelined.

template <int F, bool RELU>
__global__ __launch_bounds__(256)
void agg_f16(const _Float16* __restrict__ h, const int* __restrict__ row_start,
             const int* __restrict__ csr_src, const float* __restrict__ dinv,
             const float* __restrict__ bias, _Float16* __restrict__ out, int n) {
    constexpr int LPN = F / 4;
    constexpr int NPW = 64 / LPN;
    int wave = blockIdx.x * 4 + (threadIdx.x >> 6);
    int lane = threadIdx.x & 63;
    int sub  = lane / LPN;
    int fi   = lane - sub * LPN;
    int node = wave * NPW + sub;
    if (sub >= NPW || node >= n) return;
    int f = fi * 4;
    const _Float16* hf = h + f;

    f32x4 acc = {0.f, 0.f, 0.f, 0.f};
    int e0 = row_start[node], e1 = row_start[node + 1];
    int e = e0;
    for (; e + 4 <= e1; e += 4) {
        int s0 = csr_src[e + 0];
        int s1 = csr_src[e + 1];
        int s2 = csr_src[e + 2];
        int s3 = csr_src[e + 3];
        f16x4 v0 = *(const f16x4*)&hf[(size_t)s0 * F];
        f16x4 v1 = *(const f16x4*)&hf[(size_t)s1 * F];
        f16x4 v2 = *(const f16x4*)&hf[(size_t)s2 * F];
        f16x4 v3 = *(const f16x4*)&hf[(size_t)s3 * F];
        acc += __builtin_convertvector(v0, f32x4);
        acc += __builtin_convertvector(v1, f32x4);
        acc += __builtin_convertvector(v2, f32x4);
        acc += __builtin_convertvector(v3, f32x4);
    }
    for (; e < e1; ++e) {
        int s = csr_src[e];
        f16x4 v = *(const f16x4*)&hf[(size_t)s * F];
        acc += __builtin_convertvector(v, f32x4);
    }
    float dn = dinv[node];
    f32x4 b4 = *(const f32x4*)&bias[f];
    acc = acc * dn + b4;
    if (RELU) {
#pragma unroll
        for (int j = 0; j < 4; ++j) acc[j] = fmaxf(acc[j], 0.f);
    }
    f16x4 o;
#pragma unroll
    for (int j = 0; j < 4; ++j) o[j] = (_Float16)acc[j];
    *(f16x4*)&out[(size_t)node * F + f] = o;
}

// ---------------- tiny layer-4 helpers ----------------

__global__ void gemm_small(const _Float16* __restrict__ A, const float* __restrict__ B,
                           const float* __restrict__ dinv, float* __restrict__ C,
                           int M, int K) {
    int m = blockIdx.x * 256 + threadIdx.x;
    if (m >= M) return;
    float a0 = 0.f, a1 = 0.f, a2 = 0.f;
    for (int k = 0; k < K; ++k) {
        float a = (float)A[(size_t)m * K + k];
        a0 += a * B[0 * K + k];
        a1 += a * B[1 * K + k];
        a2 += a * B[2 * K + k];
    }
    float dv = dinv[m];
    C[(size_t)m * 3 + 0] = a0 * dv;
    C[(size_t)m * 3 + 1] = a1 * dv;
    C[(size_t)m * 3 + 2] = a2 * dv;
}

__global__ void agg_f3(const float* __restrict__ h, const int* __restrict__ row_start,
                       const int* __restrict__ csr_src, const float* __restrict__ dinv,
                       const float* __restrict__ bias, float* __restrict__ out, int n) {
    int i = blockIdx.x * 256 + threadIdx.x;
    if (i >= n * 3) return;
    int node = i / 3;
    int f = i - node * 3;
    float acc = 0.f;
    int e1 = row_start[node + 1];
    for (int e = row_start[node]; e < e1; ++e) {
        int s = csr_src[e];
        acc += h[(size_t)s * 3 + f];
    }
    out[i] = acc * dinv[node] + bias[f];
}

// ---------------------------------------------------------------------------

extern "C" void kernel_launch(void* const* d_in, const int* in_sizes, int n_in,
                              void* d_out, int out_size, void* d_ws, size_t ws_size,
                              hipStream_t stream) {
    const float* x   = (const float*)d_in[0];
    const int*   ei  = (const int*)d_in[1];
    const float* W1  = (const float*)d_in[2];
    const float* b1  = (const float*)d_in[3];
    const float* W1b = (const float*)d_in[4];
    const float* b1b = (const float*)d_in[5];
    const float* W2b = (const float*)d_in[6];
    const float* b2b = (const float*)d_in[7];
    const float* W2  = (const float*)d_in[8];
    const float* b2  = (const float*)d_in[9];
    float* out = (float*)d_out;

    const int F_IN = 500, H1 = 200, H2 = 100, H3 = 40;
    const int N = in_sizes[0] / F_IN;
    const int E = in_sizes[1] / 2;
    const int* src = ei;
    const int* dst = ei + E;

    size_t off = 0;
    auto alloc = [&](size_t bytes) -> void* {
        void* p = (char*)d_ws + off;
        off += (bytes + 255) & ~(size_t)255;
        return p;
    };
    int*   cnt       = (int*)  alloc((size_t)N * 4);
    int*   row_start = (int*)  alloc((size_t)(N + 1) * 4);
    int*   fill      = (int*)  alloc((size_t)N * 4);
    int*   partial   = (int*)  alloc(128 * 4);
    float* dinv      = (float*)alloc((size_t)N * 4);
    int*   csr_src   = (int*)  alloc((size_t)(E + N) * 4);
    unsigned short* wh1 = (unsigned short*)alloc(208 * 512 * 2);
    unsigned short* wl1 = (unsigned short*)alloc(208 * 512 * 2);
    unsigned short* wh2 = (unsigned short*)alloc(112 * 224 * 2);
    unsigned short* wl2 = (unsigned short*)alloc(112 * 224 * 2);
    unsigned short* wh3 = (unsigned short*)alloc(48 * 128 * 2);
    unsigned short* wl3 = (unsigned short*)alloc(48 * 128 * 2);
    _Float16* h16   = (_Float16*)alloc((size_t)N * H1 * 2);  // gemm outputs (scaled fp16)
    _Float16* act16 = (_Float16*)alloc((size_t)N * H1 * 2);  // agg outputs (fp16)
    float*    bufC  = (float*)   alloc((size_t)N * 3 * 4);   // layer-4 gemm out

    int gN  = (N + 255) / 256;
    int gE  = (E + 255) / 256;
    int gEN = (E + N + 255) / 256;
    int nb  = (N + 1023) / 1024;

    // --- CSR build ---
    k_init <<<gN, 256, 0, stream>>>(cnt, fill, N);
    k_count<<<gE, 256, 0, stream>>>(dst, cnt, E);
    k_scan1<<<nb, 256, 0, stream>>>(cnt, row_start, partial, dinv, N);
    k_scan2<<<1, 128, 0, stream>>>(partial, nb);
    k_scan3<<<gN, 256, 0, stream>>>(row_start, partial, N, E + N);
    k_fill <<<gEN, 256, 0, stream>>>(src, dst, row_start, fill, csr_src, E, N);

    // --- weight decomposition ---
    k_wdec<<<(208 * 512 + 255) / 256, 256, 0, stream>>>(W1,  H1, F_IN, wh1, wl1, 208, 512);
    k_wdec<<<(112 * 224 + 255) / 256, 256, 0, stream>>>(W1b, H2, H1,   wh2, wl2, 112, 224);
    k_wdec<<<( 48 * 128 + 255) / 256, 256, 0, stream>>>(W2b, H3, H2,   wh3, wl3,  48, 128);

    const int gG = (N + 127) / 128;

    // --- layer 1 ---
    gemm_mfma<13, float><<<gG, 512, 0, stream>>>(x, F_IN, N, F_IN, wh1, wl1, 512,
                                                 dinv, h16, H1, H1);
    agg_f16<200, true><<<(N + 3) / 4, 256, 0, stream>>>(h16, row_start, csr_src, dinv,
                                                        b1, act16, N);
    // --- layer 2 ---
    gemm_mfma<7, _Float16><<<gG, 512, 0, stream>>>(act16, H1, N, H1, wh2, wl2, 224,
                                                   dinv, h16, H2, H2);
    agg_f16<100, true><<<(N / 2 + 3) / 4, 256, 0, stream>>>(h16, row_start, csr_src, dinv,
                                                            b1b, act16, N);
    // --- layer 3 ---
    gemm_mfma<3, _Float16><<<gG, 512, 0, stream>>>(act16, H2, N, H2, wh3, wl3, 128,
                                                   dinv, h16, H3, H3);
    {
        int waves = (N + 5) / 6, blocks = (waves + 3) / 4;
        agg_f16<40, true><<<blocks, 256, 0, stream>>>(h16, row_start, csr_src, dinv,
                                                      b2b, act16, N);
    }
    // --- layer 4 ---
    gemm_small<<<(N + 255) / 256, 256, 0, stream>>>(act16, W2, dinv, bufC, N, H3);
    agg_f3<<<(N * 3 + 255) / 256, 256, 0, stream>>>(bufC, row_start, csr_src, dinv,
                                                    b2, out, N);
}